// Round 1
// baseline (137.381 us; speedup 1.0000x reference)
//
#include <hip/hip_runtime.h>
#include <math.h>

#define S_LEN  4096
#define NCH    64
#define TILE_S 64
#define RPT    8           // s-rows per thread (halved from 16 -> acc 24 VGPRs)
#define TY     8           // 512 threads = 8 waves
#define HALO_L 31
#define STAGE  (TILE_S + 61)   // 125 staged rows (32000 B LDS -> 4 blocks/CU)
#define WLEN   (61 + RPT)      // 69 window rows per thread
#define PRE    12              // preloaded window depth (4-tap lookahead)

// 106 fused filter taps, computed on HOST (fp64, bit-matching numpy's index
// math — validated in earlier rounds, absmax 1.56e-2 vs 1.03e-1 threshold) and
// passed BY VALUE -> kernarg segment -> scalar s_load in kernel.
struct WtArgs { float w6[62]; float w3[32]; float w1[12]; };

// ---------------------------------------------------------------------------
// Round-4: occupancy push. Prior version: RPT=16 -> 48 acc VGPRs + ~21 window
// -> VGPR in the (64,128] band -> launch_bounds(512,4) -> 4 waves/SIMD; the
// ds_read sliding-window chain + per-tap weight s_loads were under-hidden and
// the stage/compute/store phases serialized per CU (cwt ~74us vs ~27us memory
// roofline). This version: RPT=8 (acc 24 + win ~13 + addr -> est <64 VGPR),
// launch_bounds(512,8) -> 8 waves/SIMD, 4 blocks/CU (LDS 32KB). TILE_S=64
// raises halo read-amp to 1.95x, compensated by a bijective XCD swizzle
// (2048 blocks, 2048%8==0): adjacent s-tiles of the same batch land on the
// same XCD -> 61-row halo re-reads hit that XCD's L2.
// All indices remain compile-time via template recursion (round-3 lesson:
// dynamic indexing -> scratch allocas).
// ---------------------------------------------------------------------------

template <int T, int R>
struct FmaR {
  static __device__ __forceinline__ void run(const WtArgs& W, const float (&win)[WLEN],
                                             float (&a6)[RPT], float (&a3)[RPT],
                                             float (&a1)[RPT]) {
    a6[R] = fmaf(W.w6[T], win[T + R], a6[R]);
    if constexpr (T >= 15 && T <= 46) a3[R] = fmaf(W.w3[T - 15], win[T + R], a3[R]);
    if constexpr (T >= 25 && T <= 36) a1[R] = fmaf(W.w1[T - 25], win[T + R], a1[R]);
    FmaR<T, R + 1>::run(W, win, a6, a3, a1);
  }
};
template <int T>
struct FmaR<T, RPT> {
  static __device__ __forceinline__ void run(const WtArgs&, const float (&)[WLEN],
                                             float (&)[RPT], float (&)[RPT], float (&)[RPT]) {}
};

template <int T>
struct Step {
  static __device__ __forceinline__ void run(const float* __restrict__ col, const WtArgs& W,
                                             float (&win)[WLEN], float (&a6)[RPT],
                                             float (&a3)[RPT], float (&a1)[RPT]) {
    if constexpr (T + PRE < WLEN) win[T + PRE] = col[(T + PRE) * NCH];
    FmaR<T, 0>::run(W, win, a6, a3, a1);
    Step<T + 1>::run(col, W, win, a6, a3, a1);
  }
};
template <>
struct Step<62> {
  static __device__ __forceinline__ void run(const float* __restrict__, const WtArgs&,
                                             float (&)[WLEN], float (&)[RPT],
                                             float (&)[RPT], float (&)[RPT]) {}
};

template <int K>
struct Pre {
  static __device__ __forceinline__ void run(const float* __restrict__ col, float (&win)[WLEN]) {
    win[K] = col[K * NCH];
    Pre<K + 1>::run(col, win);
  }
};
template <>
struct Pre<PRE> {
  static __device__ __forceinline__ void run(const float* __restrict__, float (&)[WLEN]) {}
};

template <int R>
struct Store {
  static __device__ __forceinline__ void run(float* __restrict__ o1, float* __restrict__ o3,
                                             float* __restrict__ o6, const float (&a6)[RPT],
                                             const float (&a3)[RPT], const float (&a1)[RPT]) {
    o1[(size_t)R * NCH] = a1[R];
    o3[(size_t)R * NCH] = a3[R];
    o6[(size_t)R * NCH] = a6[R];
    Store<R + 1>::run(o1, o3, o6, a6, a3, a1);
  }
};
template <>
struct Store<RPT> {
  static __device__ __forceinline__ void run(float* __restrict__, float* __restrict__,
                                             float* __restrict__, const float (&)[RPT],
                                             const float (&)[RPT], const float (&)[RPT]) {}
};

template <int R>
struct Zero {
  static __device__ __forceinline__ void run(float (&a6)[RPT], float (&a3)[RPT], float (&a1)[RPT]) {
    a6[R] = 0.f; a3[R] = 0.f; a1[R] = 0.f;
    Zero<R + 1>::run(a6, a3, a1);
  }
};
template <>
struct Zero<RPT> {
  static __device__ __forceinline__ void run(float (&)[RPT], float (&)[RPT], float (&)[RPT]) {}
};

__global__ __launch_bounds__(512, 8)
void cwt_main(const float* __restrict__ x, float* __restrict__ out, const WtArgs W) {
  __shared__ __align__(16) float lds[STAGE * NCH];  // 32000 B

  const int c   = threadIdx.x;        // 0..63 (lane = channel)
  const int ty  = threadIdx.y;        // 0..7 (wave)
  const int tid = ty * 64 + c;

  // Bijective XCD swizzle: HW maps hw_bid -> XCD (hw_bid % 8). Logical ids
  // 256k..256k+255 (consecutive s-tiles, same b) land on XCD k -> halo L2 hits.
  const int hw  = blockIdx.x;                 // 0..2047
  const int wg  = ((hw & 7) << 8) + (hw >> 3);
  const int sx  = wg & 63;                    // 64 s-tiles (fastest within XCD)
  const int b   = wg >> 6;                    // 32 batches
  const int s0  = sx * TILE_S;

  const float* xb = x + (size_t)b * S_LEN * NCH;
  const int row0 = s0 - HALO_L;

  // ---- stage rows [s0-31 .. s0+93] to LDS as float4 (coalesced, 2-way-free)
  float4 stg[4];
  #pragma unroll
  for (int i = 0; i < 4; ++i) {
    const int idx = tid + i * 512;            // STAGE*16 = 2000 float4 slots
    const int r = idx >> 4, q = idx & 15;
    const int row = row0 + r;
    float4 v = make_float4(0.f, 0.f, 0.f, 0.f);
    if (idx < STAGE * 16 && row >= 0 && row < S_LEN)
      v = *(const float4*)(xb + ((size_t)row * NCH + (q << 2)));
    stg[i] = v;
  }
  #pragma unroll
  for (int i = 0; i < 4; ++i) {
    const int idx = tid + i * 512;
    if (idx < STAGE * 16)
      *(float4*)(&lds[(idx >> 4) * NCH + ((idx & 15) << 2)]) = stg[i];
  }
  __syncthreads();

  // ---- streaming tap recursion, all indices compile-time ----
  const int base = ty * RPT;                 // this thread: rows base..base+68
  const float* col = &lds[base * NCH + c];   // column c, stride NCH

  float win[WLEN];
  float a6[RPT], a3[RPT], a1[RPT];
  Zero<0>::run(a6, a3, a1);
  Pre<0>::run(col, win);                     // win[0..11]
  Step<0>::run(col, W, win, a6, a3, a1);     // taps 0..61

  // ---- stores: 64 lanes x 4 B contiguous per row; planes: 0=s1, 1=s3, 2=s6
  const int srow = s0 + base;
  float* o1 = out + (((size_t)b * 3 + 0) * S_LEN + srow) * NCH + c;
  float* o3 = out + (((size_t)b * 3 + 1) * S_LEN + srow) * NCH + c;
  float* o6 = out + (((size_t)b * 3 + 2) * S_LEN + srow) * NCH + c;
  Store<0>::run(o1, o3, o6, a6, a3, a1);
}

// ---------------------------------------------------------------------------
// Host-side weight construction (runs at capture time; kernarg frozen into
// the graph). Replicates pywt/gaus1 exactly:
//   x = linspace(-5,5,1024); step = x[1]-x[0];
//   psi = -2x e^{-x^2}/(pi/2)^{1/4}; int_psi = cumsum(psi)*step (serial fp64)
//   j = (arange(10a+1)/(a*step)).astype(int64); f = f32(int_psi[j])
// Fused (conv + diff + trim): w_a[t] = -sqrt(a)*(f[t-1]-f[t]), f[-1]=f[L]=0.
// ---------------------------------------------------------------------------
extern "C" void kernel_launch(void* const* d_in, const int* in_sizes, int n_in,
                              void* d_out, int out_size, void* d_ws, size_t ws_size,
                              hipStream_t stream) {
  (void)n_in; (void)out_size; (void)d_ws; (void)ws_size;
  const float* x = (const float*)d_in[0];
  float* out = (float*)d_out;
  const int B = in_sizes[0] / (S_LEN * NCH);   // 32

  WtArgs W;
  {
    static double ip[1024];
    const double delta = 10.0 / 1023.0;
    const double step  = (-5.0 + delta) + 5.0;       // == numpy x[1]-x[0]
    const double cn    = pow(3.141592653589793 * 0.5, 0.25);
    double s = 0.0;
    for (int i = 0; i < 1024; ++i) {
      const double xi  = (i == 1023) ? 5.0 : ((double)i * delta - 5.0);
      const double psi = (-2.0 * xi) * exp(-(xi * xi)) / cn;
      s += psi;
      ip[i] = s * step;
    }
    const int   as_[3] = {6, 3, 1};
    const int   lf_[3] = {61, 31, 11};               // taps t = 0..lf
    float*      wp_[3] = {W.w6, W.w3, W.w1};
    for (int si = 0; si < 3; ++si) {
      const double denom = (double)as_[si] * step;
      const float  sqa   = (float)sqrt((double)as_[si]);
      const int    lf    = lf_[si];
      for (int t = 0; t <= lf; ++t) {
        float km1 = 0.f, kt = 0.f;
        if (t >= 1)      km1 = (float)ip[(long)(((double)(t - 1)) / denom)];
        if (t <= lf - 1) kt  = (float)ip[(long)(((double)t) / denom)];
        wp_[si][t] = -sqa * (km1 - kt);
      }
    }
  }

  const int nblk = (S_LEN / TILE_S) * B;       // 64 * 32 = 2048 (divisible by 8)
  dim3 grid(nblk);
  dim3 block(NCH, TY);                         // 512 threads = 8 waves
  hipLaunchKernelGGL(cwt_main, grid, block, 0, stream, x, out, W);
}